// Round 1
// baseline (253.507 us; speedup 1.0000x reference)
//
#include <hip/hip_runtime.h>
#include <hip/hip_bf16.h>
#include <math.h>

#define SEQ   2048
#define BATCH 2
#define CDIM  1024
#define NH    16
#define HD    64

typedef __attribute__((ext_vector_type(8))) short bf16x8;
typedef __attribute__((ext_vector_type(4))) float f32x4;
typedef __attribute__((ext_vector_type(4))) short short4v;

__device__ __forceinline__ short f2bf(float f) {
  unsigned int x = __float_as_uint(f);
  x = (x + 0x7fffu + ((x >> 16) & 1u)) >> 16;  // round-nearest-even
  return (short)x;
}

// ---------------- f32 -> bf16 convert ----------------
__global__ void cvt_kernel(const float* __restrict__ src, short* __restrict__ dst, int n4) {
  int i = blockIdx.x * blockDim.x + threadIdx.x;
  if (i >= n4) return;
  float4 v = reinterpret_cast<const float4*>(src)[i];
  short4v o;
  o.x = f2bf(v.x); o.y = f2bf(v.y); o.z = f2bf(v.z); o.w = f2bf(v.w);
  reinterpret_cast<short4v*>(dst)[i] = o;
}

// ---------------- GEMM: C[M,N] = A[M,K] @ W[N,K]^T (both bf16 row-major) ----------------
// MODE 0: out = bf16, scattered to [B,H,T,D] (for q/k/v), blockIdx.z selects weight.
// MODE 1: out = f32 row-major [M,N] (final projection).
template<int MODE>
__global__ __launch_bounds__(256)
void gemm_bt(const short* __restrict__ A,
             const short* __restrict__ W0, const short* __restrict__ W1, const short* __restrict__ W2,
             short* __restrict__ ob0, short* __restrict__ ob1, short* __restrict__ ob2,
             float* __restrict__ of)
{
  constexpr int K = CDIM;
  const short* W;
  short* outb = nullptr;
  if (MODE == 0) {
    int z = blockIdx.z;
    W    = (z == 0) ? W0  : (z == 1) ? W1  : W2;
    outb = (z == 0) ? ob0 : (z == 1) ? ob1 : ob2;
  } else {
    W = W0;
  }
  const int m0 = blockIdx.y * 128;
  const int n0 = blockIdx.x * 128;

  __shared__ short As[128 * 40];
  __shared__ short Bs[128 * 40];

  const int tid  = threadIdx.x;
  const int lane = tid & 63;
  const int wid  = tid >> 6;
  const int wr   = wid >> 1;   // wave row (0..1), 64 rows each
  const int wc   = wid & 1;    // wave col (0..1), 64 cols each
  const int rl   = lane & 15;
  const int g    = lane >> 4;

  f32x4 acc[4][4];
#pragma unroll
  for (int i = 0; i < 4; ++i)
#pragma unroll
    for (int j = 0; j < 4; ++j)
      acc[i][j] = (f32x4){0.f, 0.f, 0.f, 0.f};

  const int srow = tid >> 2;         // 0..63
  const int scol = (tid & 3) * 8;    // 0,8,16,24

  for (int kt = 0; kt < K / 32; ++kt) {
    const int k0 = kt * 32;
    *(bf16x8*)&As[srow * 40 + scol]        = *(const bf16x8*)&A[(size_t)(m0 + srow) * K + k0 + scol];
    *(bf16x8*)&As[(srow + 64) * 40 + scol] = *(const bf16x8*)&A[(size_t)(m0 + srow + 64) * K + k0 + scol];
    *(bf16x8*)&Bs[srow * 40 + scol]        = *(const bf16x8*)&W[(size_t)(n0 + srow) * K + k0 + scol];
    *(bf16x8*)&Bs[(srow + 64) * 40 + scol] = *(const bf16x8*)&W[(size_t)(n0 + srow + 64) * K + k0 + scol];
    __syncthreads();

    bf16x8 af[4], bfr[4];
#pragma unroll
    for (int mi = 0; mi < 4; ++mi)
      af[mi] = *(const bf16x8*)&As[(wr * 64 + mi * 16 + rl) * 40 + g * 8];
#pragma unroll
    for (int nj = 0; nj < 4; ++nj)
      bfr[nj] = *(const bf16x8*)&Bs[(wc * 64 + nj * 16 + rl) * 40 + g * 8];
#pragma unroll
    for (int mi = 0; mi < 4; ++mi)
#pragma unroll
      for (int nj = 0; nj < 4; ++nj)
        acc[mi][nj] = __builtin_amdgcn_mfma_f32_16x16x32_bf16(af[mi], bfr[nj], acc[mi][nj], 0, 0, 0);
    __syncthreads();
  }

  // epilogue: D row = g*4 + r, col = rl within each 16x16 tile
#pragma unroll
  for (int mi = 0; mi < 4; ++mi) {
#pragma unroll
    for (int nj = 0; nj < 4; ++nj) {
#pragma unroll
      for (int r = 0; r < 4; ++r) {
        const int gm = m0 + wr * 64 + mi * 16 + g * 4 + r;
        const int gn = n0 + wc * 64 + nj * 16 + rl;
        const float val = acc[mi][nj][r];
        if (MODE == 0) {
          const int b = gm >> 11, t = gm & 2047;
          const int h = gn >> 6,  d = gn & 63;
          outb[(((size_t)(b * NH + h)) * SEQ + t) * HD + d] = f2bf(val);
        } else {
          of[(size_t)gm * CDIM + gn] = val;
        }
      }
    }
  }
}

// ---------------- flash attention, causal ----------------
// grid: (T/64, B*H). block: 256 (4 waves x 16 q-rows). q/k/v: [B,H,T,D] bf16.
__global__ __launch_bounds__(256)
void attn_kernel(const short* __restrict__ q, const short* __restrict__ k,
                 const short* __restrict__ v, short* __restrict__ yb)
{
  const int bh  = blockIdx.y;            // b*NH + h
  const int q0b = blockIdx.x * 64;
  const int tid = threadIdx.x;
  const int lane = tid & 63;
  const int wid  = tid >> 6;
  const int q0w  = q0b + wid * 16;
  const int rl   = lane & 15;
  const int g    = lane >> 4;

  const short* Qp = q + (size_t)bh * SEQ * HD;
  const short* Kp = k + (size_t)bh * SEQ * HD;
  const short* Vp = v + (size_t)bh * SEQ * HD;

  __shared__ short Ks[64 * 72];
  __shared__ short Vt[64 * 72];          // transposed: Vt[d][key]
  __shared__ short Ps[4][16 * 72];

  // preload Q fragments (2 k-steps of 32)
  bf16x8 qf[2];
  qf[0] = *(const bf16x8*)&Qp[(size_t)(q0w + rl) * HD + g * 8];
  qf[1] = *(const bf16x8*)&Qp[(size_t)(q0w + rl) * HD + 32 + g * 8];

  float m_run[4], l_run[4];
  f32x4 acc[4];
#pragma unroll
  for (int r = 0; r < 4; ++r) { m_run[r] = -INFINITY; l_run[r] = 0.f; }
#pragma unroll
  for (int nt = 0; nt < 4; ++nt) acc[nt] = (f32x4){0.f, 0.f, 0.f, 0.f};

  const float scale = 0.125f;            // 1/sqrt(64)
  const int srow = tid >> 3;             // 0..31
  const int scol = (tid & 7) * 8;        // 0..56
  const int kb_max = q0b + 63;

  for (int kb = 0; kb <= kb_max; kb += 64) {
    __syncthreads();   // previous PV reads of Ks/Vt done
    // stage K rows (row-major) and V transposed
    *(bf16x8*)&Ks[srow * 72 + scol]        = *(const bf16x8*)&Kp[(size_t)(kb + srow) * HD + scol];
    *(bf16x8*)&Ks[(srow + 32) * 72 + scol] = *(const bf16x8*)&Kp[(size_t)(kb + srow + 32) * HD + scol];
    {
      bf16x8 va = *(const bf16x8*)&Vp[(size_t)(kb + srow) * HD + scol];
      bf16x8 vb2 = *(const bf16x8*)&Vp[(size_t)(kb + srow + 32) * HD + scol];
#pragma unroll
      for (int j = 0; j < 8; ++j) {
        Vt[(scol + j) * 72 + srow]      = va[j];
        Vt[(scol + j) * 72 + srow + 32] = vb2[j];
      }
    }
    __syncthreads();

    // S = Q K^T  (4 col-tiles of 16 keys, 2 d-steps)
    f32x4 s_[4];
#pragma unroll
    for (int ct = 0; ct < 4; ++ct) {
      s_[ct] = (f32x4){0.f, 0.f, 0.f, 0.f};
#pragma unroll
      for (int ds = 0; ds < 2; ++ds) {
        bf16x8 kf = *(const bf16x8*)&Ks[(ct * 16 + rl) * 72 + ds * 32 + g * 8];
        s_[ct] = __builtin_amdgcn_mfma_f32_16x16x32_bf16(qf[ds], kf, s_[ct], 0, 0, 0);
      }
    }

    // scale + causal mask + tile row max
    float pmax[4] = {-INFINITY, -INFINITY, -INFINITY, -INFINITY};
#pragma unroll
    for (int ct = 0; ct < 4; ++ct) {
#pragma unroll
      for (int r = 0; r < 4; ++r) {
        const int key = kb + ct * 16 + rl;
        const int qq  = q0w + g * 4 + r;
        float sv = s_[ct][r] * scale;
        sv = (key <= qq) ? sv : -INFINITY;
        s_[ct][r] = sv;
        pmax[r] = fmaxf(pmax[r], sv);
      }
    }
#pragma unroll
    for (int r = 0; r < 4; ++r) {
      pmax[r] = fmaxf(pmax[r], __shfl_xor(pmax[r], 1));
      pmax[r] = fmaxf(pmax[r], __shfl_xor(pmax[r], 2));
      pmax[r] = fmaxf(pmax[r], __shfl_xor(pmax[r], 4));
      pmax[r] = fmaxf(pmax[r], __shfl_xor(pmax[r], 8));
    }

    float f_[4];
#pragma unroll
    for (int r = 0; r < 4; ++r) {
      const float mnew = fmaxf(m_run[r], pmax[r]);
      f_[r] = __expf(m_run[r] - mnew);
      m_run[r] = mnew;
      float su = 0.f;
#pragma unroll
      for (int ct = 0; ct < 4; ++ct) {
        const float p = __expf(s_[ct][r] - mnew);
        s_[ct][r] = p;
        su += p;
      }
      su += __shfl_xor(su, 1);
      su += __shfl_xor(su, 2);
      su += __shfl_xor(su, 4);
      su += __shfl_xor(su, 8);
      l_run[r] = l_run[r] * f_[r] + su;
    }
#pragma unroll
    for (int nt = 0; nt < 4; ++nt)
#pragma unroll
      for (int r = 0; r < 4; ++r)
        acc[nt][r] *= f_[r];

    // write P (bf16) to per-wave LDS, A-fragment layout read follows
#pragma unroll
    for (int ct = 0; ct < 4; ++ct)
#pragma unroll
      for (int r = 0; r < 4; ++r)
        Ps[wid][(g * 4 + r) * 72 + ct * 16 + rl] = f2bf(s_[ct][r]);
    __syncthreads();

    // O += P V
#pragma unroll
    for (int ks = 0; ks < 2; ++ks) {
      bf16x8 pf = *(const bf16x8*)&Ps[wid][rl * 72 + ks * 32 + g * 8];
#pragma unroll
      for (int nt = 0; nt < 4; ++nt) {
        bf16x8 vf = *(const bf16x8*)&Vt[(nt * 16 + rl) * 72 + ks * 32 + g * 8];
        acc[nt] = __builtin_amdgcn_mfma_f32_16x16x32_bf16(pf, vf, acc[nt], 0, 0, 0);
      }
    }
  }

  // epilogue: normalize, write y as bf16 [B,T,C] with c = h*64 + d
  const int b = bh >> 4, h = bh & 15;
#pragma unroll
  for (int r = 0; r < 4; ++r) {
    const float inv = 1.0f / l_run[r];
    const int qq = q0w + g * 4 + r;
#pragma unroll
    for (int nt = 0; nt < 4; ++nt) {
      const float o = acc[nt][r] * inv;
      yb[((size_t)b * SEQ + qq) * CDIM + h * HD + nt * 16 + rl] = f2bf(o);
    }
  }
}

extern "C" void kernel_launch(void* const* d_in, const int* in_sizes, int n_in,
                              void* d_out, int out_size, void* d_ws, size_t ws_size,
                              hipStream_t stream) {
  const float* x  = (const float*)d_in[0];
  const float* Wq = (const float*)d_in[1];
  const float* Wk = (const float*)d_in[2];
  const float* Wv = (const float*)d_in[3];
  const float* Wo = (const float*)d_in[4];
  float* out = (float*)d_out;

  char* ws = (char*)d_ws;
  short* xb  = (short*)(ws);
  short* Wqb = (short*)(ws + ((size_t)8  << 20));
  short* Wkb = (short*)(ws + ((size_t)10 << 20));
  short* Wvb = (short*)(ws + ((size_t)12 << 20));
  short* Wob = (short*)(ws + ((size_t)14 << 20));
  short* qb  = (short*)(ws + ((size_t)16 << 20));
  short* kbp = (short*)(ws + ((size_t)24 << 20));
  short* vbp = (short*)(ws + ((size_t)32 << 20));
  short* yb  = (short*)(ws + ((size_t)40 << 20));

  // converts: x = 4M elems, each W = 1M elems
  cvt_kernel<<<4096, 256, 0, stream>>>(x,  xb,  1048576);
  cvt_kernel<<<1024, 256, 0, stream>>>(Wq, Wqb, 262144);
  cvt_kernel<<<1024, 256, 0, stream>>>(Wk, Wkb, 262144);
  cvt_kernel<<<1024, 256, 0, stream>>>(Wv, Wvb, 262144);
  cvt_kernel<<<1024, 256, 0, stream>>>(Wo, Wob, 262144);

  // q/k/v projections: [4096,1024] x [1024,1024]^T -> [B,H,T,D]
  gemm_bt<0><<<dim3(8, 32, 3), 256, 0, stream>>>(xb, Wqb, Wkb, Wvb, qb, kbp, vbp, nullptr);

  // causal flash attention -> yb [B,T,C] bf16
  attn_kernel<<<dim3(32, 32), 256, 0, stream>>>(qb, kbp, vbp, yb);

  // output projection -> f32 d_out
  gemm_bt<1><<<dim3(8, 32, 1), 256, 0, stream>>>(yb, Wob, nullptr, nullptr,
                                                 nullptr, nullptr, nullptr, out);
}

// Round 2
// 196.147 us; speedup vs baseline: 1.2924x; 1.2924x over previous
//
#include <hip/hip_runtime.h>
#include <hip/hip_bf16.h>
#include <math.h>

#define SEQ   2048
#define CDIM  1024
#define NH    16
#define HD    64

typedef __attribute__((ext_vector_type(8))) short bf16x8;
typedef __attribute__((ext_vector_type(4))) float f32x4;
typedef __attribute__((ext_vector_type(4))) short short4v;

__device__ __forceinline__ short f2bf(float f) {
  unsigned int x = __float_as_uint(f);
  x = (x + 0x7fffu + ((x >> 16) & 1u)) >> 16;  // round-nearest-even
  return (short)x;
}

// ---------------- f32 -> bf16 convert ----------------
__global__ void cvt_kernel(const float* __restrict__ src, short* __restrict__ dst, int n4) {
  int i = blockIdx.x * blockDim.x + threadIdx.x;
  if (i >= n4) return;
  float4 v = reinterpret_cast<const float4*>(src)[i];
  short4v o;
  o.x = f2bf(v.x); o.y = f2bf(v.y); o.z = f2bf(v.z); o.w = f2bf(v.w);
  reinterpret_cast<short4v*>(dst)[i] = o;
}

// ---------------- GEMM: C[M,N] = A[M,K] @ W[N,K]^T (both bf16 row-major) ----------------
// MODE 0: out = bf16. z=0 (Q), z=1 (K): scattered to [B,H,T,D]. z=2 (V): TRANSPOSED to [B,H,D,T].
// MODE 1: out = f32 row-major [M,N] (final projection).
template<int MODE>
__global__ __launch_bounds__(256)
void gemm_bt(const short* __restrict__ A,
             const short* __restrict__ W0, const short* __restrict__ W1, const short* __restrict__ W2,
             short* __restrict__ ob0, short* __restrict__ ob1, short* __restrict__ ob2,
             float* __restrict__ of)
{
  constexpr int K = CDIM;
  const int z = (MODE == 0) ? blockIdx.z : 0;
  const short* W;
  short* outb = nullptr;
  if (MODE == 0) {
    W    = (z == 0) ? W0  : (z == 1) ? W1  : W2;
    outb = (z == 0) ? ob0 : (z == 1) ? ob1 : ob2;
  } else {
    W = W0;
  }
  const int m0 = blockIdx.y * 128;
  const int n0 = blockIdx.x * 128;

  __shared__ short As[128 * 40];
  __shared__ short Bs[128 * 40];

  const int tid  = threadIdx.x;
  const int lane = tid & 63;
  const int wid  = tid >> 6;
  const int wr   = wid >> 1;   // wave row (0..1), 64 rows each
  const int wc   = wid & 1;    // wave col (0..1), 64 cols each
  const int rl   = lane & 15;
  const int g    = lane >> 4;

  f32x4 acc[4][4];
#pragma unroll
  for (int i = 0; i < 4; ++i)
#pragma unroll
    for (int j = 0; j < 4; ++j)
      acc[i][j] = (f32x4){0.f, 0.f, 0.f, 0.f};

  const int srow = tid >> 2;         // 0..63
  const int scol = (tid & 3) * 8;    // 0,8,16,24

  for (int kt = 0; kt < K / 32; ++kt) {
    const int k0 = kt * 32;
    *(bf16x8*)&As[srow * 40 + scol]        = *(const bf16x8*)&A[(size_t)(m0 + srow) * K + k0 + scol];
    *(bf16x8*)&As[(srow + 64) * 40 + scol] = *(const bf16x8*)&A[(size_t)(m0 + srow + 64) * K + k0 + scol];
    *(bf16x8*)&Bs[srow * 40 + scol]        = *(const bf16x8*)&W[(size_t)(n0 + srow) * K + k0 + scol];
    *(bf16x8*)&Bs[(srow + 64) * 40 + scol] = *(const bf16x8*)&W[(size_t)(n0 + srow + 64) * K + k0 + scol];
    __syncthreads();

    bf16x8 af[4], bfr[4];
#pragma unroll
    for (int mi = 0; mi < 4; ++mi)
      af[mi] = *(const bf16x8*)&As[(wr * 64 + mi * 16 + rl) * 40 + g * 8];
#pragma unroll
    for (int nj = 0; nj < 4; ++nj)
      bfr[nj] = *(const bf16x8*)&Bs[(wc * 64 + nj * 16 + rl) * 40 + g * 8];
#pragma unroll
    for (int mi = 0; mi < 4; ++mi)
#pragma unroll
      for (int nj = 0; nj < 4; ++nj)
        acc[mi][nj] = __builtin_amdgcn_mfma_f32_16x16x32_bf16(af[mi], bfr[nj], acc[mi][nj], 0, 0, 0);
    __syncthreads();
  }

  // epilogue: D row = g*4 + r, col = rl within each 16x16 tile
#pragma unroll
  for (int mi = 0; mi < 4; ++mi) {
#pragma unroll
    for (int nj = 0; nj < 4; ++nj) {
      const int gmb = m0 + wr * 64 + mi * 16 + g * 4;   // 4 consecutive rows
      const int gn  = n0 + wc * 64 + nj * 16 + rl;
      if (MODE == 0 && z == 2) {
        // V: write transposed [B,H,D,T], pack 4 consecutive t
        short4v pk;
#pragma unroll
        for (int r = 0; r < 4; ++r) pk[r] = f2bf(acc[mi][nj][r]);
        const int b = gmb >> 11, t = gmb & 2047;
        const int h = gn >> 6,  d = gn & 63;
        *(short4v*)&outb[(((size_t)(b * NH + h)) * HD + d) * SEQ + t] = pk;
      } else {
#pragma unroll
        for (int r = 0; r < 4; ++r) {
          const int gm = gmb + r;
          const float val = acc[mi][nj][r];
          if (MODE == 0) {
            const int b = gm >> 11, t = gm & 2047;
            const int h = gn >> 6,  d = gn & 63;
            outb[(((size_t)(b * NH + h)) * SEQ + t) * HD + d] = f2bf(val);
          } else {
            of[(size_t)gm * CDIM + gn] = val;
          }
        }
      }
    }
  }
}

// ---------------- flash attention, causal ----------------
// grid: (T/128, B*H). block: 256 (4 waves x 32 q-rows). q,k: [B,H,T,D]; vt: [B,H,D,T].
__global__ __launch_bounds__(256)
void attn_kernel(const short* __restrict__ q, const short* __restrict__ k,
                 const short* __restrict__ vt, short* __restrict__ yb)
{
  const int bh  = blockIdx.y;                          // b*NH + h
  const int q0b = (gridDim.x - 1 - blockIdx.x) * 128;  // heavy blocks first
  const int tid = threadIdx.x;
  const int lane = tid & 63;
  const int wid  = tid >> 6;
  const int q0w  = q0b + wid * 32;
  const int rl   = lane & 15;
  const int g    = lane >> 4;

  const short* Qp = q  + (size_t)bh * SEQ * HD;
  const short* Kp = k  + (size_t)bh * SEQ * HD;
  const short* Vp = vt + (size_t)bh * HD * SEQ;        // [d][t]

  __shared__ short Ks[64 * 72];        // [key][d]
  __shared__ short Vs[64 * 72];        // [d][key]
  __shared__ short Ps[4][32 * 72];     // per-wave [q][key]

  // Q fragments: 2 m-tiles x 2 k-steps
  bf16x8 qf[2][2];
#pragma unroll
  for (int m = 0; m < 2; ++m)
#pragma unroll
    for (int ds = 0; ds < 2; ++ds)
      qf[m][ds] = *(const bf16x8*)&Qp[(size_t)(q0w + m * 16 + rl) * HD + ds * 32 + g * 8];

  float m_run[2][4], l_run[2][4];
  f32x4 acc[2][4];
#pragma unroll
  for (int m = 0; m < 2; ++m)
#pragma unroll
    for (int r = 0; r < 4; ++r) { m_run[m][r] = -INFINITY; l_run[m][r] = 0.f; }
#pragma unroll
  for (int m = 0; m < 2; ++m)
#pragma unroll
    for (int nt = 0; nt < 4; ++nt) acc[m][nt] = (f32x4){0.f, 0.f, 0.f, 0.f};

  const float scale = 0.125f;          // 1/sqrt(64)
  const int srow = tid >> 3;           // 0..31
  const int scol = (tid & 7) * 8;      // 0..56
  const int kend = q0b + 128;

  // prefetch tile kb=0 into registers
  bf16x8 k0 = *(const bf16x8*)&Kp[(size_t)srow * HD + scol];
  bf16x8 k1 = *(const bf16x8*)&Kp[(size_t)(srow + 32) * HD + scol];
  bf16x8 v0 = *(const bf16x8*)&Vp[(size_t)srow * SEQ + scol];
  bf16x8 v1 = *(const bf16x8*)&Vp[(size_t)(srow + 32) * SEQ + scol];

  for (int kb = 0; kb < kend; kb += 64) {
    __syncthreads();                   // prior tile's PV reads done
    *(bf16x8*)&Ks[srow * 72 + scol]        = k0;
    *(bf16x8*)&Ks[(srow + 32) * 72 + scol] = k1;
    *(bf16x8*)&Vs[srow * 72 + scol]        = v0;
    *(bf16x8*)&Vs[(srow + 32) * 72 + scol] = v1;
    __syncthreads();

    // issue next tile's loads — latency hides under compute below
    if (kb + 64 < kend) {
      const int kn = kb + 64;
      k0 = *(const bf16x8*)&Kp[(size_t)(kn + srow) * HD + scol];
      k1 = *(const bf16x8*)&Kp[(size_t)(kn + srow + 32) * HD + scol];
      v0 = *(const bf16x8*)&Vp[(size_t)srow * SEQ + kn + scol];
      v1 = *(const bf16x8*)&Vp[(size_t)(srow + 32) * SEQ + kn + scol];
    }

    if (kb <= q0w + 31) {              // wave-uniform: skip fully-masked tiles
      // ---- S = Q K^T ----
      f32x4 s_[2][4];
#pragma unroll
      for (int m = 0; m < 2; ++m)
#pragma unroll
        for (int ct = 0; ct < 4; ++ct) s_[m][ct] = (f32x4){0.f, 0.f, 0.f, 0.f};
      __builtin_amdgcn_s_setprio(1);
#pragma unroll
      for (int ct = 0; ct < 4; ++ct) {
#pragma unroll
        for (int ds = 0; ds < 2; ++ds) {
          bf16x8 kf = *(const bf16x8*)&Ks[(ct * 16 + rl) * 72 + ds * 32 + g * 8];
#pragma unroll
          for (int m = 0; m < 2; ++m)
            s_[m][ct] = __builtin_amdgcn_mfma_f32_16x16x32_bf16(qf[m][ds], kf, s_[m][ct], 0, 0, 0);
        }
      }
      __builtin_amdgcn_s_setprio(0);

      // ---- online softmax ----
      float f_[2][4];
#pragma unroll
      for (int m = 0; m < 2; ++m) {
        float pmax[4] = {-INFINITY, -INFINITY, -INFINITY, -INFINITY};
#pragma unroll
        for (int ct = 0; ct < 4; ++ct) {
#pragma unroll
          for (int r = 0; r < 4; ++r) {
            const int key = kb + ct * 16 + rl;
            const int qq  = q0w + m * 16 + g * 4 + r;
            float sv = s_[m][ct][r] * scale;
            sv = (key <= qq) ? sv : -INFINITY;
            s_[m][ct][r] = sv;
            pmax[r] = fmaxf(pmax[r], sv);
          }
        }
#pragma unroll
        for (int r = 0; r < 4; ++r) {
          pmax[r] = fmaxf(pmax[r], __shfl_xor(pmax[r], 1));
          pmax[r] = fmaxf(pmax[r], __shfl_xor(pmax[r], 2));
          pmax[r] = fmaxf(pmax[r], __shfl_xor(pmax[r], 4));
          pmax[r] = fmaxf(pmax[r], __shfl_xor(pmax[r], 8));
        }
#pragma unroll
        for (int r = 0; r < 4; ++r) {
          const float mnew = fmaxf(m_run[m][r], pmax[r]);
          f_[m][r] = __expf(m_run[m][r] - mnew);
          m_run[m][r] = mnew;
          float su = 0.f;
#pragma unroll
          for (int ct = 0; ct < 4; ++ct) {
            const float p = __expf(s_[m][ct][r] - mnew);
            s_[m][ct][r] = p;
            su += p;
          }
          su += __shfl_xor(su, 1);
          su += __shfl_xor(su, 2);
          su += __shfl_xor(su, 4);
          su += __shfl_xor(su, 8);
          l_run[m][r] = l_run[m][r] * f_[m][r] + su;
        }
#pragma unroll
        for (int nt = 0; nt < 4; ++nt)
#pragma unroll
          for (int r = 0; r < 4; ++r)
            acc[m][nt][r] *= f_[m][r];
      }

      // ---- P -> per-wave LDS (A-fragment layout) ----
#pragma unroll
      for (int m = 0; m < 2; ++m)
#pragma unroll
        for (int ct = 0; ct < 4; ++ct)
#pragma unroll
          for (int r = 0; r < 4; ++r)
            Ps[wid][(m * 16 + g * 4 + r) * 72 + ct * 16 + rl] = f2bf(s_[m][ct][r]);

      // ---- O += P V ----  (no barrier needed: Ps is per-wave, Vs staged above)
      __builtin_amdgcn_s_setprio(1);
#pragma unroll
      for (int ks = 0; ks < 2; ++ks) {
        bf16x8 pf[2];
#pragma unroll
        for (int m = 0; m < 2; ++m)
          pf[m] = *(const bf16x8*)&Ps[wid][(m * 16 + rl) * 72 + ks * 32 + g * 8];
#pragma unroll
        for (int nt = 0; nt < 4; ++nt) {
          bf16x8 vf = *(const bf16x8*)&Vs[(nt * 16 + rl) * 72 + ks * 32 + g * 8];
#pragma unroll
          for (int m = 0; m < 2; ++m)
            acc[m][nt] = __builtin_amdgcn_mfma_f32_16x16x32_bf16(pf[m], vf, acc[m][nt], 0, 0, 0);
        }
      }
      __builtin_amdgcn_s_setprio(0);
    }
  }

  // epilogue: normalize, write y as bf16 [B,T,C] with c = h*64 + d
  const int b = bh >> 4, h = bh & 15;
#pragma unroll
  for (int m = 0; m < 2; ++m) {
#pragma unroll
    for (int r = 0; r < 4; ++r) {
      const float inv = 1.0f / l_run[m][r];
      const int qq = q0w + m * 16 + g * 4 + r;
#pragma unroll
      for (int nt = 0; nt < 4; ++nt) {
        const float o = acc[m][nt][r] * inv;
        yb[((size_t)b * SEQ + qq) * CDIM + h * HD + nt * 16 + rl] = f2bf(o);
      }
    }
  }
}

extern "C" void kernel_launch(void* const* d_in, const int* in_sizes, int n_in,
                              void* d_out, int out_size, void* d_ws, size_t ws_size,
                              hipStream_t stream) {
  const float* x  = (const float*)d_in[0];
  const float* Wq = (const float*)d_in[1];
  const float* Wk = (const float*)d_in[2];
  const float* Wv = (const float*)d_in[3];
  const float* Wo = (const float*)d_in[4];
  float* out = (float*)d_out;

  char* ws = (char*)d_ws;
  short* xb  = (short*)(ws);
  short* Wqb = (short*)(ws + ((size_t)8  << 20));
  short* Wkb = (short*)(ws + ((size_t)10 << 20));
  short* Wvb = (short*)(ws + ((size_t)12 << 20));
  short* Wob = (short*)(ws + ((size_t)14 << 20));
  short* qb  = (short*)(ws + ((size_t)16 << 20));
  short* kbp = (short*)(ws + ((size_t)24 << 20));
  short* vtp = (short*)(ws + ((size_t)32 << 20));   // [B,H,D,T]
  short* yb  = (short*)(ws + ((size_t)40 << 20));

  // converts: x = 4M elems, each W = 1M elems
  cvt_kernel<<<4096, 256, 0, stream>>>(x,  xb,  1048576);
  cvt_kernel<<<1024, 256, 0, stream>>>(Wq, Wqb, 262144);
  cvt_kernel<<<1024, 256, 0, stream>>>(Wk, Wkb, 262144);
  cvt_kernel<<<1024, 256, 0, stream>>>(Wv, Wvb, 262144);
  cvt_kernel<<<1024, 256, 0, stream>>>(Wo, Wob, 262144);

  // q/k/v projections: [4096,1024] x [1024,1024]^T; V written transposed
  gemm_bt<0><<<dim3(8, 32, 3), 256, 0, stream>>>(xb, Wqb, Wkb, Wvb, qb, kbp, vtp, nullptr);

  // causal flash attention -> yb [B,T,C] bf16
  attn_kernel<<<dim3(16, 32), 256, 0, stream>>>(qb, kbp, vtp, yb);

  // output projection -> f32 d_out
  gemm_bt<1><<<dim3(8, 32, 1), 256, 0, stream>>>(yb, Wob, nullptr, nullptr,
                                                 nullptr, nullptr, nullptr, out);
}

// Round 4
// 145.303 us; speedup vs baseline: 1.7447x; 1.3499x over previous
//
#include <hip/hip_runtime.h>
#include <hip/hip_bf16.h>
#include <math.h>

#define SEQ   2048
#define CDIM  1024
#define NH    16
#define HD    64

typedef __attribute__((ext_vector_type(8))) short bf16x8;
typedef __attribute__((ext_vector_type(4))) float f32x4;
typedef __attribute__((ext_vector_type(4))) short short4v;

__device__ __forceinline__ short f2bf(float f) {
  unsigned int x = __float_as_uint(f);
  x = (x + 0x7fffu + ((x >> 16) & 1u)) >> 16;  // round-nearest-even
  return (short)x;
}

// ---------------- f32 -> bf16 convert ----------------
__global__ void cvt_kernel(const float* __restrict__ src, short* __restrict__ dst, int n4) {
  int i = blockIdx.x * blockDim.x + threadIdx.x;
  if (i >= n4) return;
  float4 v = reinterpret_cast<const float4*>(src)[i];
  short4v o;
  o.x = f2bf(v.x); o.y = f2bf(v.y); o.z = f2bf(v.z); o.w = f2bf(v.w);
  reinterpret_cast<short4v*>(dst)[i] = o;
}

// ---------------- GEMM: C[M,N] = A[M,K] @ W[N,K]^T (both bf16 row-major) ----------------
// MODE 0: out = bf16. z=0 (Q), z=1 (K): scattered to [B,H,T,D]. z=2 (V): TRANSPOSED to [B,H,D,T].
// MODE 1: out = f32 row-major [M,N] (final projection).
template<int MODE>
__global__ __launch_bounds__(256)
void gemm_bt(const short* __restrict__ A,
             const short* __restrict__ W0, const short* __restrict__ W1, const short* __restrict__ W2,
             short* __restrict__ ob0, short* __restrict__ ob1, short* __restrict__ ob2,
             float* __restrict__ of)
{
  constexpr int K = CDIM;
  const int z = (MODE == 0) ? blockIdx.z : 0;
  const short* W;
  short* outb = nullptr;
  if (MODE == 0) {
    W    = (z == 0) ? W0  : (z == 1) ? W1  : W2;
    outb = (z == 0) ? ob0 : (z == 1) ? ob1 : ob2;
  } else {
    W = W0;
  }
  const int m0 = blockIdx.y * 128;
  const int n0 = blockIdx.x * 128;

  __shared__ short As[128 * 40];
  __shared__ short Bs[128 * 40];

  const int tid  = threadIdx.x;
  const int lane = tid & 63;
  const int wid  = tid >> 6;
  const int wr   = wid >> 1;
  const int wc   = wid & 1;
  const int rl   = lane & 15;
  const int g    = lane >> 4;

  f32x4 acc[4][4];
#pragma unroll
  for (int i = 0; i < 4; ++i)
#pragma unroll
    for (int j = 0; j < 4; ++j)
      acc[i][j] = (f32x4){0.f, 0.f, 0.f, 0.f};

  const int srow = tid >> 2;
  const int scol = (tid & 3) * 8;

  for (int kt = 0; kt < K / 32; ++kt) {
    const int k0 = kt * 32;
    *(bf16x8*)&As[srow * 40 + scol]        = *(const bf16x8*)&A[(size_t)(m0 + srow) * K + k0 + scol];
    *(bf16x8*)&As[(srow + 64) * 40 + scol] = *(const bf16x8*)&A[(size_t)(m0 + srow + 64) * K + k0 + scol];
    *(bf16x8*)&Bs[srow * 40 + scol]        = *(const bf16x8*)&W[(size_t)(n0 + srow) * K + k0 + scol];
    *(bf16x8*)&Bs[(srow + 64) * 40 + scol] = *(const bf16x8*)&W[(size_t)(n0 + srow + 64) * K + k0 + scol];
    __syncthreads();

    bf16x8 af[4], bfr[4];
#pragma unroll
    for (int mi = 0; mi < 4; ++mi)
      af[mi] = *(const bf16x8*)&As[(wr * 64 + mi * 16 + rl) * 40 + g * 8];
#pragma unroll
    for (int nj = 0; nj < 4; ++nj)
      bfr[nj] = *(const bf16x8*)&Bs[(wc * 64 + nj * 16 + rl) * 40 + g * 8];
#pragma unroll
    for (int mi = 0; mi < 4; ++mi)
#pragma unroll
      for (int nj = 0; nj < 4; ++nj)
        acc[mi][nj] = __builtin_amdgcn_mfma_f32_16x16x32_bf16(af[mi], bfr[nj], acc[mi][nj], 0, 0, 0);
    __syncthreads();
  }

#pragma unroll
  for (int mi = 0; mi < 4; ++mi) {
#pragma unroll
    for (int nj = 0; nj < 4; ++nj) {
      const int gmb = m0 + wr * 64 + mi * 16 + g * 4;
      const int gn  = n0 + wc * 64 + nj * 16 + rl;
      if (MODE == 0 && z == 2) {
        short4v pk;
#pragma unroll
        for (int r = 0; r < 4; ++r) pk[r] = f2bf(acc[mi][nj][r]);
        const int b = gmb >> 11, t = gmb & 2047;
        const int h = gn >> 6,  d = gn & 63;
        *(short4v*)&outb[(((size_t)(b * NH + h)) * HD + d) * SEQ + t] = pk;
      } else {
#pragma unroll
        for (int r = 0; r < 4; ++r) {
          const int gm = gmb + r;
          const float val = acc[mi][nj][r];
          if (MODE == 0) {
            const int b = gm >> 11, t = gm & 2047;
            const int h = gn >> 6,  d = gn & 63;
            outb[(((size_t)(b * NH + h)) * SEQ + t) * HD + d] = f2bf(val);
          } else {
            of[(size_t)gm * CDIM + gn] = val;
          }
        }
      }
    }
  }
}

// ---------------- flash attention, causal, paired q-blocks ----------------
// grid: (16 pairs, B*H). block: 256 (4 waves x 16 q-rows per q-set).
// Block p handles q-blocks jA=p (light) and jB=31-p (heavy); one shared KV loop.
// Every block does exactly (jA+1)+(jB+1) = 33 tile-processes -> perfect balance.
// Softmax math identical to round-2 (proven): full reduce + rescale every tile.
__global__ __launch_bounds__(256)
void attn_kernel(const short* __restrict__ q, const short* __restrict__ k,
                 const short* __restrict__ vt, short* __restrict__ yb)
{
  const int bh  = blockIdx.y;
  const int pp  = blockIdx.x;          // pair index 0..15
  const int jA  = pp;                  // light q-block
  const int jB  = 31 - pp;             // heavy q-block
  const int tid = threadIdx.x;
  const int lane = tid & 63;
  const int wid  = tid >> 6;
  const int rl   = lane & 15;
  const int g    = lane >> 4;

  const short* Qp = q  + (size_t)bh * SEQ * HD;
  const short* Kp = k  + (size_t)bh * SEQ * HD;
  const short* Vp = vt + (size_t)bh * HD * SEQ;    // [d][t]

  __shared__ short Ks[64 * 72];        // [key][d]
  __shared__ short Vs[64 * 72];        // [d][key]
  __shared__ short Ps[4][2][16 * 72];  // [wave][set][q][key]

  const int q0A = jA * 64 + wid * 16;  // wave's 16 rows in set A
  const int q0B = jB * 64 + wid * 16;

  bf16x8 qfA[2], qfB[2];
#pragma unroll
  for (int ds = 0; ds < 2; ++ds) {
    qfA[ds] = *(const bf16x8*)&Qp[(size_t)(q0A + rl) * HD + ds * 32 + g * 8];
    qfB[ds] = *(const bf16x8*)&Qp[(size_t)(q0B + rl) * HD + ds * 32 + g * 8];
  }

  f32x4 accA[4], accB[4];
  float mA[4], lA[4], mB[4], lB[4];
#pragma unroll
  for (int r = 0; r < 4; ++r) { mA[r] = -INFINITY; lA[r] = 0.f; mB[r] = -INFINITY; lB[r] = 0.f; }
#pragma unroll
  for (int nt = 0; nt < 4; ++nt) { accA[nt] = (f32x4){0,0,0,0}; accB[nt] = (f32x4){0,0,0,0}; }

  const float scale = 0.125f;          // 1/sqrt(64)
  const int srow = tid >> 3;           // 0..31
  const int scol = (tid & 7) * 8;      // 0..56

  // per-tile work for one q-set — round-2 math: reduce + rescale every tile.
  auto process = [&](bf16x8 (&qf)[2], f32x4 (&acc)[4], float (&m_run)[4], float (&l_run)[4],
                     bool diag, short* PsW) {
    // ---- S = Q K^T ----
    f32x4 s_[4];
#pragma unroll
    for (int ct = 0; ct < 4; ++ct) s_[ct] = (f32x4){0, 0, 0, 0};
    __builtin_amdgcn_s_setprio(1);
#pragma unroll
    for (int ct = 0; ct < 4; ++ct)
#pragma unroll
      for (int ds = 0; ds < 2; ++ds) {
        bf16x8 kf = *(const bf16x8*)&Ks[(ct * 16 + rl) * 72 + ds * 32 + g * 8];
        s_[ct] = __builtin_amdgcn_mfma_f32_16x16x32_bf16(qf[ds], kf, s_[ct], 0, 0, 0);
      }
    __builtin_amdgcn_s_setprio(0);

    // ---- scale (+ mask on diagonal tile) + row max ----
    float pm[4] = {-INFINITY, -INFINITY, -INFINITY, -INFINITY};
#pragma unroll
    for (int ct = 0; ct < 4; ++ct)
#pragma unroll
      for (int r = 0; r < 4; ++r) {
        float sv = s_[ct][r] * scale;
        if (diag) {
          const int lq = wid * 16 + g * 4 + r;   // local row within 64-block
          const int lk = ct * 16 + rl;           // local key
          sv = (lk <= lq) ? sv : -INFINITY;
        }
        s_[ct][r] = sv;
        pm[r] = fmaxf(pm[r], sv);
      }
#pragma unroll
    for (int r = 0; r < 4; ++r) {
      pm[r] = fmaxf(pm[r], __shfl_xor(pm[r], 1));
      pm[r] = fmaxf(pm[r], __shfl_xor(pm[r], 2));
      pm[r] = fmaxf(pm[r], __shfl_xor(pm[r], 4));
      pm[r] = fmaxf(pm[r], __shfl_xor(pm[r], 8));
      const float mnew = fmaxf(m_run[r], pm[r]);
      const float f = __expf(m_run[r] - mnew);
      m_run[r] = mnew;
      l_run[r] *= f;
#pragma unroll
      for (int nt = 0; nt < 4; ++nt) acc[nt][r] *= f;
    }

    // ---- exp + per-lane partial l + P write ----
#pragma unroll
    for (int ct = 0; ct < 4; ++ct) {
      const int c = ct * 16 + rl;
#pragma unroll
      for (int r = 0; r < 4; ++r) {
        const float p = __expf(s_[ct][r] - m_run[r]);
        l_run[r] += p;
        PsW[(g * 4 + r) * 72 + c] = f2bf(p);
      }
    }

    // ---- O += P V ----  (Ps per-wave: no barrier)
    __builtin_amdgcn_s_setprio(1);
#pragma unroll
    for (int ks = 0; ks < 2; ++ks) {
      bf16x8 pf = *(const bf16x8*)&PsW[rl * 72 + ks * 32 + g * 8];
#pragma unroll
      for (int nt = 0; nt < 4; ++nt) {
        bf16x8 vf = *(const bf16x8*)&Vs[(nt * 16 + rl) * 72 + ks * 32 + g * 8];
        acc[nt] = __builtin_amdgcn_mfma_f32_16x16x32_bf16(pf, vf, acc[nt], 0, 0, 0);
      }
    }
    __builtin_amdgcn_s_setprio(0);
  };

  auto epilogue = [&](f32x4 (&acc)[4], float (&l_run)[4], int q0w) {
    const int b = bh >> 4, h = bh & 15;
#pragma unroll
    for (int r = 0; r < 4; ++r) {
      float lr = l_run[r];
      lr += __shfl_xor(lr, 1);
      lr += __shfl_xor(lr, 2);
      lr += __shfl_xor(lr, 4);
      lr += __shfl_xor(lr, 8);
      const float inv = 1.0f / lr;
      const int qq = q0w + g * 4 + r;
#pragma unroll
      for (int nt = 0; nt < 4; ++nt)
        yb[((size_t)b * SEQ + qq) * CDIM + h * HD + nt * 16 + rl] = f2bf(acc[nt][r] * inv);
    }
  };

  // prefetch tile 0
  bf16x8 k0 = *(const bf16x8*)&Kp[(size_t)srow * HD + scol];
  bf16x8 k1 = *(const bf16x8*)&Kp[(size_t)(srow + 32) * HD + scol];
  bf16x8 v0 = *(const bf16x8*)&Vp[(size_t)srow * SEQ + scol];
  bf16x8 v1 = *(const bf16x8*)&Vp[(size_t)(srow + 32) * SEQ + scol];

  for (int t = 0; t <= jB; ++t) {
    __syncthreads();                   // prior tile's reads done
    *(bf16x8*)&Ks[srow * 72 + scol]        = k0;
    *(bf16x8*)&Ks[(srow + 32) * 72 + scol] = k1;
    *(bf16x8*)&Vs[srow * 72 + scol]        = v0;
    *(bf16x8*)&Vs[(srow + 32) * 72 + scol] = v1;
    __syncthreads();

    if (t < jB) {                      // issue next tile's loads early
      const int kn = (t + 1) * 64;
      k0 = *(const bf16x8*)&Kp[(size_t)(kn + srow) * HD + scol];
      k1 = *(const bf16x8*)&Kp[(size_t)(kn + srow + 32) * HD + scol];
      v0 = *(const bf16x8*)&Vp[(size_t)srow * SEQ + kn + scol];
      v1 = *(const bf16x8*)&Vp[(size_t)(srow + 32) * SEQ + kn + scol];
    }

    process(qfB, accB, mB, lB, t == jB, &Ps[wid][0][0]);   // heavy set: every tile
    if (t <= jA)
      process(qfA, accA, mA, lA, t == jA, &Ps[wid][1][0]); // light set: prefix
  }

  epilogue(accB, lB, q0B);
  epilogue(accA, lA, q0A);
}

extern "C" void kernel_launch(void* const* d_in, const int* in_sizes, int n_in,
                              void* d_out, int out_size, void* d_ws, size_t ws_size,
                              hipStream_t stream) {
  const float* x  = (const float*)d_in[0];
  const float* Wq = (const float*)d_in[1];
  const float* Wk = (const float*)d_in[2];
  const float* Wv = (const float*)d_in[3];
  const float* Wo = (const float*)d_in[4];
  float* out = (float*)d_out;

  char* ws = (char*)d_ws;
  short* xb  = (short*)(ws);
  short* Wqb = (short*)(ws + ((size_t)8  << 20));
  short* Wkb = (short*)(ws + ((size_t)10 << 20));
  short* Wvb = (short*)(ws + ((size_t)12 << 20));
  short* Wob = (short*)(ws + ((size_t)14 << 20));
  short* qb  = (short*)(ws + ((size_t)16 << 20));
  short* kbp = (short*)(ws + ((size_t)24 << 20));
  short* vtp = (short*)(ws + ((size_t)32 << 20));   // [B,H,D,T]
  short* yb  = (short*)(ws + ((size_t)40 << 20));

  cvt_kernel<<<4096, 256, 0, stream>>>(x,  xb,  1048576);
  cvt_kernel<<<1024, 256, 0, stream>>>(Wq, Wqb, 262144);
  cvt_kernel<<<1024, 256, 0, stream>>>(Wk, Wkb, 262144);
  cvt_kernel<<<1024, 256, 0, stream>>>(Wv, Wvb, 262144);
  cvt_kernel<<<1024, 256, 0, stream>>>(Wo, Wob, 262144);

  gemm_bt<0><<<dim3(8, 32, 3), 256, 0, stream>>>(xb, Wqb, Wkb, Wvb, qb, kbp, vtp, nullptr);

  attn_kernel<<<dim3(16, 32), 256, 0, stream>>>(qb, kbp, vtp, yb);

  gemm_bt<1><<<dim3(8, 32, 1), 256, 0, stream>>>(yb, Wob, nullptr, nullptr,
                                                 nullptr, nullptr, nullptr, out);
}

// Round 5
// 137.814 us; speedup vs baseline: 1.8395x; 1.0543x over previous
//
#include <hip/hip_runtime.h>
#include <hip/hip_bf16.h>
#include <math.h>

#define SEQ   2048
#define CDIM  1024
#define NH    16
#define HD    64

typedef __attribute__((ext_vector_type(8))) short bf16x8;
typedef __attribute__((ext_vector_type(4))) float f32x4;
typedef __attribute__((ext_vector_type(4))) short short4v;

// native cast -> compiler emits packed v_cvt_pk_bf16_f32 for pairs (RNE)
__device__ __forceinline__ short f2bf(float f) {
  return (short)__builtin_bit_cast(unsigned short, __float2bfloat16(f));
}

// async global->LDS, 16B per lane. dest = wave-uniform base + lane*16.
__device__ __forceinline__ void glds16(const short* g, short* l) {
  __builtin_amdgcn_global_load_lds(
      (const __attribute__((address_space(1))) unsigned int*)g,
      (__attribute__((address_space(3))) unsigned int*)l, 16, 0, 0);
}

// ---------------- f32 -> bf16 convert ----------------
__global__ void cvt_kernel(const float* __restrict__ src, short* __restrict__ dst, int n4) {
  int i = blockIdx.x * blockDim.x + threadIdx.x;
  if (i >= n4) return;
  float4 v = reinterpret_cast<const float4*>(src)[i];
  short4v o;
  o.x = f2bf(v.x); o.y = f2bf(v.y); o.z = f2bf(v.z); o.w = f2bf(v.w);
  reinterpret_cast<short4v*>(dst)[i] = o;
}

// ---------------- GEMM: C[M,N] = A[M,K] @ W[N,K]^T (both bf16 row-major) ----------------
// Staging via global_load_lds dwordx4, linear [128][32] LDS (BK=32).
// MODE 0: out = bf16. z=0 (Q), z=1 (K): scattered to [B,H,T,D]. z=2 (V): TRANSPOSED to [B,H,D,T].
// MODE 1: out = f32 row-major [M,N] (final projection).
template<int MODE>
__global__ __launch_bounds__(256)
void gemm_bt(const short* __restrict__ A,
             const short* __restrict__ W0, const short* __restrict__ W1, const short* __restrict__ W2,
             short* __restrict__ ob0, short* __restrict__ ob1, short* __restrict__ ob2,
             float* __restrict__ of)
{
  constexpr int K = CDIM;
  const int z = (MODE == 0) ? blockIdx.z : 0;
  const short* W;
  short* outb = nullptr;
  if (MODE == 0) {
    W    = (z == 0) ? W0  : (z == 1) ? W1  : W2;
    outb = (z == 0) ? ob0 : (z == 1) ? ob1 : ob2;
  } else {
    W = W0;
  }
  const int m0 = blockIdx.y * 128;
  const int n0 = blockIdx.x * 128;

  __shared__ __align__(16) short As[128 * 32];
  __shared__ __align__(16) short Bs[128 * 32];

  const int tid  = threadIdx.x;
  const int lane = tid & 63;
  const int wid  = tid >> 6;
  const int wr   = wid >> 1;
  const int wc   = wid & 1;
  const int rl   = lane & 15;
  const int g    = lane >> 4;

  f32x4 acc[4][4];
#pragma unroll
  for (int i = 0; i < 4; ++i)
#pragma unroll
    for (int j = 0; j < 4; ++j)
      acc[i][j] = (f32x4){0.f, 0.f, 0.f, 0.f};

  // staging: wave w covers rows [w*32, w*32+32), 2 loads of 16 rows each.
  const int lrow = lane >> 2;          // 0..15
  const int lcol = (lane & 3) * 8;     // shorts: 0,8,16,24
  const int arow = wid * 32 + lrow;

  for (int kt = 0; kt < K / 32; ++kt) {
    const int k0 = kt * 32;
    glds16(&A[(size_t)(m0 + arow) * K + k0 + lcol],      &As[(wid * 32) * 32]);
    glds16(&A[(size_t)(m0 + arow + 16) * K + k0 + lcol], &As[(wid * 32 + 16) * 32]);
    glds16(&W[(size_t)(n0 + arow) * K + k0 + lcol],      &Bs[(wid * 32) * 32]);
    glds16(&W[(size_t)(n0 + arow + 16) * K + k0 + lcol], &Bs[(wid * 32 + 16) * 32]);
    __syncthreads();   // drains vmcnt (gload_lds) for all waves

    bf16x8 af[4], bfr[4];
#pragma unroll
    for (int mi = 0; mi < 4; ++mi)
      af[mi] = *(const bf16x8*)&As[(wr * 64 + mi * 16 + rl) * 32 + g * 8];
#pragma unroll
    for (int nj = 0; nj < 4; ++nj)
      bfr[nj] = *(const bf16x8*)&Bs[(wc * 64 + nj * 16 + rl) * 32 + g * 8];
#pragma unroll
    for (int mi = 0; mi < 4; ++mi)
#pragma unroll
      for (int nj = 0; nj < 4; ++nj)
        acc[mi][nj] = __builtin_amdgcn_mfma_f32_16x16x32_bf16(af[mi], bfr[nj], acc[mi][nj], 0, 0, 0);
    __syncthreads();   // LDS reads done before next iter's staging
  }

#pragma unroll
  for (int mi = 0; mi < 4; ++mi) {
#pragma unroll
    for (int nj = 0; nj < 4; ++nj) {
      const int gmb = m0 + wr * 64 + mi * 16 + g * 4;
      const int gn  = n0 + wc * 64 + nj * 16 + rl;
      if (MODE == 0 && z == 2) {
        short4v pk;
#pragma unroll
        for (int r = 0; r < 4; ++r) pk[r] = f2bf(acc[mi][nj][r]);
        const int b = gmb >> 11, t = gmb & 2047;
        const int h = gn >> 6,  d = gn & 63;
        *(short4v*)&outb[(((size_t)(b * NH + h)) * HD + d) * SEQ + t] = pk;
      } else {
#pragma unroll
        for (int r = 0; r < 4; ++r) {
          const int gm = gmb + r;
          const float val = acc[mi][nj][r];
          if (MODE == 0) {
            const int b = gm >> 11, t = gm & 2047;
            const int h = gn >> 6,  d = gn & 63;
            outb[(((size_t)(b * NH + h)) * SEQ + t) * HD + d] = f2bf(val);
          } else {
            of[(size_t)gm * CDIM + gn] = val;
          }
        }
      }
    }
  }
}

// ---------------- flash attention, causal, paired q-blocks ----------------
// grid: (16 pairs, B*H). block: 256 (4 waves x 16 q-rows per q-set).
// Block p handles q-blocks jA=p (light) and jB=31-p (heavy); one shared KV loop.
// Skip-rescale is FP-identical to full reduce when no lane's partial max grows.
__global__ __launch_bounds__(256)
void attn_kernel(const short* __restrict__ q, const short* __restrict__ k,
                 const short* __restrict__ vt, short* __restrict__ yb)
{
  const int bh  = blockIdx.y;
  const int pp  = blockIdx.x;          // pair index 0..15
  const int jA  = pp;                  // light q-block
  const int jB  = 31 - pp;             // heavy q-block
  const int tid = threadIdx.x;
  const int lane = tid & 63;
  const int wid  = tid >> 6;
  const int rl   = lane & 15;
  const int g    = lane >> 4;

  const short* Qp = q  + (size_t)bh * SEQ * HD;
  const short* Kp = k  + (size_t)bh * SEQ * HD;
  const short* Vp = vt + (size_t)bh * HD * SEQ;    // [d][t]

  __shared__ short Ks[64 * 72];        // [key][d]
  __shared__ short Vs[64 * 72];        // [d][key]
  __shared__ short Ps[4][2][16 * 72];  // [wave][set][q][key]

  const int q0A = jA * 64 + wid * 16;
  const int q0B = jB * 64 + wid * 16;

  bf16x8 qfA[2], qfB[2];
#pragma unroll
  for (int ds = 0; ds < 2; ++ds) {
    qfA[ds] = *(const bf16x8*)&Qp[(size_t)(q0A + rl) * HD + ds * 32 + g * 8];
    qfB[ds] = *(const bf16x8*)&Qp[(size_t)(q0B + rl) * HD + ds * 32 + g * 8];
  }

  f32x4 accA[4], accB[4];
  float mA[4], lA[4], mB[4], lB[4];
#pragma unroll
  for (int r = 0; r < 4; ++r) { mA[r] = -INFINITY; lA[r] = 0.f; mB[r] = -INFINITY; lB[r] = 0.f; }
#pragma unroll
  for (int nt = 0; nt < 4; ++nt) { accA[nt] = (f32x4){0,0,0,0}; accB[nt] = (f32x4){0,0,0,0}; }

  const float scale = 0.125f;          // 1/sqrt(64)
  const int srow = tid >> 3;           // 0..31
  const int scol = (tid & 7) * 8;      // 0..56

  auto process = [&](bf16x8 (&qf)[2], f32x4 (&acc)[4], float (&m_run)[4], float (&l_run)[4],
                     bool diag, short* PsW) {
    // ---- S = Q K^T ----
    f32x4 s_[4];
#pragma unroll
    for (int ct = 0; ct < 4; ++ct) s_[ct] = (f32x4){0, 0, 0, 0};
    __builtin_amdgcn_s_setprio(1);
#pragma unroll
    for (int ct = 0; ct < 4; ++ct)
#pragma unroll
      for (int ds = 0; ds < 2; ++ds) {
        bf16x8 kf = *(const bf16x8*)&Ks[(ct * 16 + rl) * 72 + ds * 32 + g * 8];
        s_[ct] = __builtin_amdgcn_mfma_f32_16x16x32_bf16(qf[ds], kf, s_[ct], 0, 0, 0);
      }
    __builtin_amdgcn_s_setprio(0);

    // ---- scale (+ mask on diagonal tile) + per-lane partial max ----
    float pm[4] = {-INFINITY, -INFINITY, -INFINITY, -INFINITY};
#pragma unroll
    for (int ct = 0; ct < 4; ++ct)
#pragma unroll
      for (int r = 0; r < 4; ++r) {
        float sv = s_[ct][r] * scale;
        if (diag) {
          const int lq = wid * 16 + g * 4 + r;
          const int lk = ct * 16 + rl;
          sv = (lk <= lq) ? sv : -INFINITY;
        }
        s_[ct][r] = sv;
        pm[r] = fmaxf(pm[r], sv);
      }

    // ---- reduce + rescale only when some lane's max grew.
    // When skipped: reduce would give mnew==m_run, f==1.0 -> FP-identical.
    bool need = false;
#pragma unroll
    for (int r = 0; r < 4; ++r) need = need || (pm[r] > m_run[r]);
    if (__any((int)need)) {
#pragma unroll
      for (int r = 0; r < 4; ++r) {
        pm[r] = fmaxf(pm[r], __shfl_xor(pm[r], 1));
        pm[r] = fmaxf(pm[r], __shfl_xor(pm[r], 2));
        pm[r] = fmaxf(pm[r], __shfl_xor(pm[r], 4));
        pm[r] = fmaxf(pm[r], __shfl_xor(pm[r], 8));
        const float mnew = fmaxf(m_run[r], pm[r]);
        const float f = __expf(m_run[r] - mnew);
        m_run[r] = mnew;
        l_run[r] *= f;
#pragma unroll
        for (int nt = 0; nt < 4; ++nt) acc[nt][r] *= f;
      }
    }

    // ---- exp + per-lane partial l + P write ----
#pragma unroll
    for (int ct = 0; ct < 4; ++ct) {
      const int c = ct * 16 + rl;
#pragma unroll
      for (int r = 0; r < 4; ++r) {
        const float p = __expf(s_[ct][r] - m_run[r]);
        l_run[r] += p;
        PsW[(g * 4 + r) * 72 + c] = f2bf(p);
      }
    }

    // ---- O += P V ----  (Ps per-wave: no barrier)
    __builtin_amdgcn_s_setprio(1);
#pragma unroll
    for (int ks = 0; ks < 2; ++ks) {
      bf16x8 pf = *(const bf16x8*)&PsW[rl * 72 + ks * 32 + g * 8];
#pragma unroll
      for (int nt = 0; nt < 4; ++nt) {
        bf16x8 vf = *(const bf16x8*)&Vs[(nt * 16 + rl) * 72 + ks * 32 + g * 8];
        acc[nt] = __builtin_amdgcn_mfma_f32_16x16x32_bf16(pf, vf, acc[nt], 0, 0, 0);
      }
    }
    __builtin_amdgcn_s_setprio(0);
  };

  auto epilogue = [&](f32x4 (&acc)[4], float (&l_run)[4], int q0w) {
    const int b = bh >> 4, h = bh & 15;
#pragma unroll
    for (int r = 0; r < 4; ++r) {
      float lr = l_run[r];
      lr += __shfl_xor(lr, 1);
      lr += __shfl_xor(lr, 2);
      lr += __shfl_xor(lr, 4);
      lr += __shfl_xor(lr, 8);
      const float inv = 1.0f / lr;
      const int qq = q0w + g * 4 + r;
#pragma unroll
      for (int nt = 0; nt < 4; ++nt)
        yb[((size_t)b * SEQ + qq) * CDIM + h * HD + nt * 16 + rl] = f2bf(acc[nt][r] * inv);
    }
  };

  // prefetch tile 0
  bf16x8 k0 = *(const bf16x8*)&Kp[(size_t)srow * HD + scol];
  bf16x8 k1 = *(const bf16x8*)&Kp[(size_t)(srow + 32) * HD + scol];
  bf16x8 v0 = *(const bf16x8*)&Vp[(size_t)srow * SEQ + scol];
  bf16x8 v1 = *(const bf16x8*)&Vp[(size_t)(srow + 32) * SEQ + scol];

  for (int t = 0; t <= jB; ++t) {
    __syncthreads();
    *(bf16x8*)&Ks[srow * 72 + scol]        = k0;
    *(bf16x8*)&Ks[(srow + 32) * 72 + scol] = k1;
    *(bf16x8*)&Vs[srow * 72 + scol]        = v0;
    *(bf16x8*)&Vs[(srow + 32) * 72 + scol] = v1;
    __syncthreads();

    if (t < jB) {
      const int kn = (t + 1) * 64;
      k0 = *(const bf16x8*)&Kp[(size_t)(kn + srow) * HD + scol];
      k1 = *(const bf16x8*)&Kp[(size_t)(kn + srow + 32) * HD + scol];
      v0 = *(const bf16x8*)&Vp[(size_t)srow * SEQ + kn + scol];
      v1 = *(const bf16x8*)&Vp[(size_t)(srow + 32) * SEQ + kn + scol];
    }

    process(qfB, accB, mB, lB, t == jB, &Ps[wid][0][0]);
    if (t <= jA)
      process(qfA, accA, mA, lA, t == jA, &Ps[wid][1][0]);
  }

  epilogue(accB, lB, q0B);
  epilogue(accA, lA, q0A);
}

extern "C" void kernel_launch(void* const* d_in, const int* in_sizes, int n_in,
                              void* d_out, int out_size, void* d_ws, size_t ws_size,
                              hipStream_t stream) {
  const float* x  = (const float*)d_in[0];
  const float* Wq = (const float*)d_in[1];
  const float* Wk = (const float*)d_in[2];
  const float* Wv = (const float*)d_in[3];
  const float* Wo = (const float*)d_in[4];
  float* out = (float*)d_out;

  char* ws = (char*)d_ws;
  short* xb  = (short*)(ws);
  short* Wqb = (short*)(ws + ((size_t)8  << 20));
  short* Wkb = (short*)(ws + ((size_t)10 << 20));
  short* Wvb = (short*)(ws + ((size_t)12 << 20));
  short* Wob = (short*)(ws + ((size_t)14 << 20));
  short* qb  = (short*)(ws + ((size_t)16 << 20));
  short* kbp = (short*)(ws + ((size_t)24 << 20));
  short* vtp = (short*)(ws + ((size_t)32 << 20));   // [B,H,D,T]
  short* yb  = (short*)(ws + ((size_t)40 << 20));

  cvt_kernel<<<4096, 256, 0, stream>>>(x,  xb,  1048576);
  cvt_kernel<<<1024, 256, 0, stream>>>(Wq, Wqb, 262144);
  cvt_kernel<<<1024, 256, 0, stream>>>(Wk, Wkb, 262144);
  cvt_kernel<<<1024, 256, 0, stream>>>(Wv, Wvb, 262144);
  cvt_kernel<<<1024, 256, 0, stream>>>(Wo, Wob, 262144);

  gemm_bt<0><<<dim3(8, 32, 3), 256, 0, stream>>>(xb, Wqb, Wkb, Wvb, qb, kbp, vtp, nullptr);

  attn_kernel<<<dim3(16, 32), 256, 0, stream>>>(qb, kbp, vtp, yb);

  gemm_bt<1><<<dim3(8, 32, 1), 256, 0, stream>>>(yb, Wob, nullptr, nullptr,
                                                 nullptr, nullptr, nullptr, out);
}